// Round 15
// baseline (74.469 us; speedup 1.0000x reference)
//
#include <hip/hip_runtime.h>

// Grouped VQ: bf16-MFMA screen + exact-fp32 rescue, v15.
// Pivot: whole 128KB group table resident in LDS (160KB/CU on gfx950),
// loaded ONCE per block; ONE barrier; then 8 waves free-run their tokens
// over all 64 ct-tiles with NO barriers / staging / global b-traffic.
// Every prior variant (v4-v14, all ~60-75us) shared a barrier-synced
// stage machine that convoyed waves; this removes it entirely.
// Block 512 thr (8 waves x 32 tokens = 256 tokens x 1 group); grid 512
// (64 chunks x 8 groups) -> 2 sequential blocks/CU (132KB LDS -> 1 res).
// Numerics unchanged (proven): d = cn64[code] + <x,-2c>_bf16 (C-folded
// MFMA), 22-bit key | 10-bit code, med3 exact top-2, EPS=0.10,
// exact-fp32 rescue in reference order.

#define NTOK   16384
#define DMODEL 512
#define NGRP   8
#define DG     64
#define NCODE  1024
#define EPS    0.10f

typedef __attribute__((ext_vector_type(8))) __bf16 bf16x8;
typedef __attribute__((ext_vector_type(4))) float  f32x4;

__device__ __forceinline__ unsigned umin_(unsigned a, unsigned b){ return a<b?a:b; }

// exact running top-2: best' = min(bo,k), sec' = median{bo, sec, k}.
__device__ __forceinline__ void top2_(unsigned& best, unsigned& sec, unsigned key)
{
    unsigned bo = best;
    best = umin_(bo, key);
    unsigned ns;
    asm("v_med3_u32 %0, %1, %2, %3" : "=v"(ns) : "v"(bo), "v"(sec), "v"(key));
    sec = ns;
}

// ---------------- prep: pack codebook into B-fragment layout (bf16) --------
// Stores -2*c. ws_b element index = (((g*64 + ct)*2 + s)*64 + lane)*8 + j
//   holds -2*cb[g][ct*16 + (lane&15)][s*32 + (lane>>4)*8 + j] as bf16.
__global__ __launch_bounds__(256) void prep_frags(
    const float* __restrict__ cb, __bf16* __restrict__ wb)
{
    int tid  = blockIdx.x * 256 + threadIdx.x;      // 0..65535
    int lane = tid & 63;
    int s    = (tid >> 6) & 1;
    int ct   = (tid >> 7) & 63;
    int g    = tid >> 13;
    int code = ct * 16 + (lane & 15);
    int k0   = s * 32 + (lane >> 4) * 8;
    const float* src = cb + ((size_t)g * NCODE + code) * DG + k0;
    bf16x8 v;
    #pragma unroll
    for (int j = 0; j < 8; ++j) v[j] = (__bf16)(-2.0f * src[j]);
    *reinterpret_cast<bf16x8*>(wb + (size_t)tid * 8) = v;
}

__global__ __launch_bounds__(256) void prep_cnorm(
    const float* __restrict__ cb, float* __restrict__ wcn)
{
    int i = blockIdx.x * 256 + threadIdx.x;         // 0..8191 (g*1024+code)
    const float4* c4 = reinterpret_cast<const float4*>(cb + (size_t)i * DG);
    float s = 0.0f;
    #pragma unroll
    for (int j = 0; j < 16; ++j) {
        float4 v = c4[j];
        s = fmaf(v.x, v.x, s); s = fmaf(v.y, v.y, s);
        s = fmaf(v.z, v.z, s); s = fmaf(v.w, v.w, s);
    }
    wcn[i] = s;
}

__device__ __forceinline__ float dotc(const float* __restrict__ a,
                                      const float* __restrict__ b)
{
    const float4* a4 = reinterpret_cast<const float4*>(a);
    const float4* b4 = reinterpret_cast<const float4*>(b);
    float s = 0.0f;
    #pragma unroll 4
    for (int j = 0; j < 16; ++j) {
        float4 u = a4[j], v = b4[j];
        s = fmaf(u.x, v.x, s); s = fmaf(u.y, v.y, s);
        s = fmaf(u.z, v.z, s); s = fmaf(u.w, v.w, s);
    }
    return s;
}

__device__ __forceinline__ bf16x8 cvt8(const float* __restrict__ p)
{
    float4 u = *reinterpret_cast<const float4*>(p);
    float4 v = *reinterpret_cast<const float4*>(p + 4);
    bf16x8 r;
    r[0]=(__bf16)u.x; r[1]=(__bf16)u.y; r[2]=(__bf16)u.z; r[3]=(__bf16)u.w;
    r[4]=(__bf16)v.x; r[5]=(__bf16)v.y; r[6]=(__bf16)v.z; r[7]=(__bf16)v.w;
    return r;
}

// ---------------- main: screen + rescue ------------------------------------
// Block = 512 threads (8 waves), each wave 32 tokens; block = 256 tokens x
// 1 group. Grid = 64 chunks * 8 groups = 512 blocks.
__global__ __launch_bounds__(512, 2) void vq_mfma_kernel(
    const float*  __restrict__ x,
    const float*  __restrict__ cb,
    const __bf16* __restrict__ wb,
    const float*  __restrict__ wcn,
    float* __restrict__ out)
{
    __shared__ __bf16 tbl[NCODE * DG];   // 128 KB: full group fragment table
    __shared__ float  cn64[NCODE];       //   4 KB

    const int tid  = threadIdx.x;
    const int lane = tid & 63;
    const int wv   = tid >> 6;           // 0..7
    const int g    = blockIdx.x & 7;
    const int chunk = blockIdx.x >> 3;

    const __bf16* wbg = wb + (size_t)g * (NCODE * DG);

    // ---- load full table into LDS (once; straight copy, coalesced) ----
    #pragma unroll
    for (int i = 0; i < 16; ++i)
        *reinterpret_cast<bf16x8*>(&tbl[i * 4096 + tid * 8]) =
            *reinterpret_cast<const bf16x8*>(wbg + i * 4096 + tid * 8);

    {   // cn+64 (screen bias; rescue uses true wcn)
        float2 v = reinterpret_cast<const float2*>(wcn + g * NCODE)[tid];
        float2 o; o.x = v.x + 64.0f; o.y = v.y + 64.0f;
        reinterpret_cast<float2*>(cn64)[tid] = o;
    }

    const int row  = lane & 15;
    const int q    = lane >> 4;
    const int k0   = q * 8;
    const int tok0 = chunk * 256 + wv * 32;

    bf16x8 aA[2], aB[2];
    #pragma unroll
    for (int s = 0; s < 2; ++s) {
        const float* xr = x + (size_t)(tok0 + s * 16 + row) * DMODEL + g * DG;
        aA[s] = cvt8(xr + k0);
        aB[s] = cvt8(xr + 32 + k0);
        asm("" : "+v"(aA[s]));
        asm("" : "+v"(aB[s]));
    }

    unsigned best[2][4], sec[2][4];
    #pragma unroll
    for (int s = 0; s < 2; ++s)
        #pragma unroll
        for (int r = 0; r < 4; ++r) { best[s][r] = 0xFFFFFFFFu; sec[s][r] = 0xFFFFFFFFu; }

    __syncthreads();     // the ONLY barrier: table + cn64 ready

    // ---- barrier-free main loop: 8 blocks of 8 cts, 2-deep DS pipeline ----
    for (int st = 0; st < 8; ++st) {
        const __bf16* bufp = &tbl[st * 8192];
        bf16x8 cb0_ = *reinterpret_cast<const bf16x8*>(bufp + lane * 8);
        bf16x8 cb1_ = *reinterpret_cast<const bf16x8*>(bufp + 512 + lane * 8);
        float  cnv_ = cn64[st * 128 + row];
        #pragma unroll
        for (int ctl_ = 0; ctl_ < 8; ++ctl_) {
            bf16x8 nb0_, nb1_; float ncv_;
            if (ctl_ < 7) {
                nb0_ = *reinterpret_cast<const bf16x8*>(bufp + (ctl_ + 1) * 1024 + lane * 8);
                nb1_ = *reinterpret_cast<const bf16x8*>(bufp + (ctl_ + 1) * 1024 + 512 + lane * 8);
                ncv_ = cn64[st * 128 + (ctl_ + 1) * 16 + row];
            }
            const int code_ = st * 128 + ctl_ * 16 + row;
            const f32x4 ci_ = {cnv_, cnv_, cnv_, cnv_};
            #pragma unroll
            for (int s_ = 0; s_ < 2; ++s_) {
                f32x4 z_ = __builtin_amdgcn_mfma_f32_16x16x32_bf16(aA[s_], cb0_, ci_, 0, 0, 0);
                f32x4 d_ = __builtin_amdgcn_mfma_f32_16x16x32_bf16(aB[s_], cb1_, z_, 0, 0, 0);
                asm("" : "+v"(d_));
                #pragma unroll
                for (int r_ = 0; r_ < 4; ++r_) {
                    unsigned key_ = (__float_as_uint(d_[r_]) & 0xFFFFFC00u) | (unsigned)code_;
                    top2_(best[s_][r_], sec[s_][r_], key_);
                }
            }
            if (ctl_ < 7) { cb0_ = nb0_; cb1_ = nb1_; cnv_ = ncv_; }
        }
    }

    // min-reduce packed keys across each 16-lane col group (q-group)
    unsigned mk[2][4];
    #pragma unroll
    for (int s = 0; s < 2; ++s)
        #pragma unroll
        for (int r = 0; r < 4; ++r) mk[s][r] = best[s][r];
    #pragma unroll
    for (int mask = 1; mask < 16; mask <<= 1) {
        #pragma unroll
        for (int s = 0; s < 2; ++s)
            #pragma unroll
            for (int r = 0; r < 4; ++r) {
                unsigned o = (unsigned)__shfl_xor((int)mk[s][r], mask, 64);
                mk[s][r] = umin_(mk[s][r], o);
            }
    }

    const float* cbg  = cb  + (size_t)g * NCODE * DG;
    const float* wcng = wcn + (size_t)g * NCODE;

    #pragma unroll
    for (int s = 0; s < 2; ++s) {
        #pragma unroll
        for (int r = 0; r < 4; ++r) {
            const unsigned m_ = mk[s][r];
            int sel = (int)(m_ & 0x3FFu);
            const float thr = __uint_as_float(m_ & 0xFFFFFC00u) + EPS;
            const float bd  = __uint_as_float(best[s][r] & 0xFFFFFC00u);
            const float sdd = __uint_as_float(sec[s][r]  & 0xFFFFFC00u);
            const bool oth = (bd <= thr && best[s][r] != m_) || (sdd <= thr);
            const unsigned long long bal = __ballot(oth);
            if (((bal >> (q * 16)) & 0xFFFFULL) != 0ULL) {
                // exact fp32 rescue among tracked candidates
                const int token = tok0 + s * 16 + q * 4 + r;
                const float* xr = x + (size_t)token * DMODEL + g * DG;
                const float xn = dotc(xr, xr);
                float ed = 1e30f; int ei = 0x7FFFFFFF;
                if (bd <= thr) {
                    const int cc = (int)(best[s][r] & 0x3FFu);
                    float dd = (xn + wcng[cc]) - 2.0f * dotc(xr, cbg + (size_t)cc * DG);
                    if (dd < ed || (dd == ed && cc < ei)) { ed = dd; ei = cc; }
                }
                if (sdd <= thr) {
                    const int cc = (int)(sec[s][r] & 0x3FFu);
                    float dd = (xn + wcng[cc]) - 2.0f * dotc(xr, cbg + (size_t)cc * DG);
                    if (dd < ed || (dd == ed && cc < ei)) { ed = dd; ei = cc; }
                }
                #pragma unroll
                for (int mask = 1; mask < 16; mask <<= 1) {
                    float pd = __shfl_xor(ed, mask, 64);
                    int   pi = __shfl_xor(ei, mask, 64);
                    if (pd < ed || (pd == ed && pi < ei)) { ed = pd; ei = pi; }
                }
                sel = ei;
            }
            // write the selected code row (16 lanes x float4 = 64 floats)
            const int token = tok0 + s * 16 + q * 4 + r;
            const float4 src = reinterpret_cast<const float4*>(cbg + (size_t)sel * DG)[row];
            reinterpret_cast<float4*>(out + (size_t)token * DMODEL + g * DG)[row] = src;
        }
    }
}

// ---------------- fp32 fallback (ws too small) -----------------------------
__global__ __launch_bounds__(512, 4) void vq_fp32_kernel(
    const float* __restrict__ x,
    const float* __restrict__ cb,
    float* __restrict__ out)
{
    __shared__ float cnl[NGRP][NCODE];
    const int tid  = threadIdx.x;
    const int lane = tid & 63;
    const int wave = tid >> 6;
    const int g    = __builtin_amdgcn_readfirstlane(wave);
    const int token = blockIdx.x * 64 + lane;
    const float* __restrict__ cbg = cb + (size_t)g * NCODE * DG;

    for (int kk = lane; kk < NCODE; kk += 64) {
        const float4* c4 = reinterpret_cast<const float4*>(cbg + kk * DG);
        float s = 0.0f;
        #pragma unroll
        for (int j = 0; j < 16; ++j) {
            float4 v = c4[j];
            s = fmaf(v.x, v.x, s); s = fmaf(v.y, v.y, s);
            s = fmaf(v.z, v.z, s); s = fmaf(v.w, v.w, s);
        }
        cnl[g][kk] = s;
    }
    __syncthreads();

    const float* xr = x + (size_t)token * DMODEL + g * DG;
    float xn = dotc(xr, xr);
    float bestv = 3.4e38f; int bidx = 0;
    for (int k = 0; k < NCODE; ++k) {
        float dist = (xn + cnl[g][k]) - 2.0f * dotc(xr, cbg + (size_t)k * DG);
        if (dist < bestv) { bestv = dist; bidx = k; }
    }
    const float4* q4 = reinterpret_cast<const float4*>(cbg + (size_t)bidx * DG);
    float4* o4 = reinterpret_cast<float4*>(out + (size_t)token * DMODEL + g * DG);
    #pragma unroll
    for (int j = 0; j < 16; ++j) o4[j] = q4[j];
}

extern "C" void kernel_launch(void* const* d_in, const int* in_sizes, int n_in,
                              void* d_out, int out_size, void* d_ws, size_t ws_size,
                              hipStream_t stream) {
    const float* x  = (const float*)d_in[0];
    const float* cb = (const float*)d_in[1];
    float* out = (float*)d_out;

    const size_t wb_bytes = (size_t)NGRP * NCODE * DG * sizeof(__bf16); // 1 MB
    const size_t cn_bytes = (size_t)NGRP * NCODE * sizeof(float);       // 32 KB
    if (ws_size < wb_bytes + cn_bytes) {
        vq_fp32_kernel<<<256, 512, 0, stream>>>(x, cb, out);
        return;
    }
    __bf16* wb  = (__bf16*)d_ws;
    float*  wcn = (float*)((char*)d_ws + wb_bytes);

    prep_frags<<<256, 256, 0, stream>>>(cb, wb);
    prep_cnorm<<<32, 256, 0, stream>>>(cb, wcn);
    vq_mfma_kernel<<<512, 512, 0, stream>>>(x, cb, wb, wcn, out);
}

// Round 16
// 71.145 us; speedup vs baseline: 1.0467x; 1.0467x over previous
//
#include <hip/hip_runtime.h>

// Grouped VQ: bf16-MFMA screen + exact-fp32 rescue, v16.
// Final TLP probe: v12 skeleton at TRUE 8 waves/SIMD. 16 tokens/wave
// (1 subtile), stage = 4 ct-tiles -> LDS 20KB -> 8 blocks/CU, grid 2048,
// lb(256,8) VGPR cap 64 (~60 working set). Cross-variant invariant:
// VALU-issue ~59K cyc/SIMD, wall = issue/VALUBusy, VALUBusy <= 40% at
// <=3 waves/SIMD. 8/SIMD either stacks duty (-> ~40us) or exposes a
// shared-resource cap (-> null, declare limit).
// Numerics unchanged (proven): d = cn64[code] + <x,-2c>_bf16 (C-folded
// MFMA), 22-bit key | 10-bit code, med3 exact top-2, EPS=0.10,
// exact-fp32 rescue in reference order.

#define NTOK   16384
#define DMODEL 512
#define NGRP   8
#define DG     64
#define NCODE  1024
#define EPS    0.10f

#define STG_ELEM 4096        // 4 ct-tiles * 1024 bf16 = 8 KB

typedef __attribute__((ext_vector_type(8))) __bf16 bf16x8;
typedef __attribute__((ext_vector_type(4))) float  f32x4;

__device__ __forceinline__ unsigned umin_(unsigned a, unsigned b){ return a<b?a:b; }

// exact running top-2: best' = min(bo,k), sec' = median{bo, sec, k}.
__device__ __forceinline__ void top2_(unsigned& best, unsigned& sec, unsigned key)
{
    unsigned bo = best;
    best = umin_(bo, key);
    unsigned ns;
    asm("v_med3_u32 %0, %1, %2, %3" : "=v"(ns) : "v"(bo), "v"(sec), "v"(key));
    sec = ns;
}

// ---------------- prep: pack codebook into B-fragment layout (bf16) --------
// Stores -2*c. ws_b element index = (((g*64 + ct)*2 + s)*64 + lane)*8 + j
//   holds -2*cb[g][ct*16 + (lane&15)][s*32 + (lane>>4)*8 + j] as bf16.
__global__ __launch_bounds__(256) void prep_frags(
    const float* __restrict__ cb, __bf16* __restrict__ wb)
{
    int tid  = blockIdx.x * 256 + threadIdx.x;      // 0..65535
    int lane = tid & 63;
    int s    = (tid >> 6) & 1;
    int ct   = (tid >> 7) & 63;
    int g    = tid >> 13;
    int code = ct * 16 + (lane & 15);
    int k0   = s * 32 + (lane >> 4) * 8;
    const float* src = cb + ((size_t)g * NCODE + code) * DG + k0;
    bf16x8 v;
    #pragma unroll
    for (int j = 0; j < 8; ++j) v[j] = (__bf16)(-2.0f * src[j]);
    *reinterpret_cast<bf16x8*>(wb + (size_t)tid * 8) = v;
}

__global__ __launch_bounds__(256) void prep_cnorm(
    const float* __restrict__ cb, float* __restrict__ wcn)
{
    int i = blockIdx.x * 256 + threadIdx.x;         // 0..8191 (g*1024+code)
    const float4* c4 = reinterpret_cast<const float4*>(cb + (size_t)i * DG);
    float s = 0.0f;
    #pragma unroll
    for (int j = 0; j < 16; ++j) {
        float4 v = c4[j];
        s = fmaf(v.x, v.x, s); s = fmaf(v.y, v.y, s);
        s = fmaf(v.z, v.z, s); s = fmaf(v.w, v.w, s);
    }
    wcn[i] = s;
}

__device__ __forceinline__ float dotc(const float* __restrict__ a,
                                      const float* __restrict__ b)
{
    const float4* a4 = reinterpret_cast<const float4*>(a);
    const float4* b4 = reinterpret_cast<const float4*>(b);
    float s = 0.0f;
    #pragma unroll 4
    for (int j = 0; j < 16; ++j) {
        float4 u = a4[j], v = b4[j];
        s = fmaf(u.x, v.x, s); s = fmaf(u.y, v.y, s);
        s = fmaf(u.z, v.z, s); s = fmaf(u.w, v.w, s);
    }
    return s;
}

__device__ __forceinline__ bf16x8 cvt8(const float* __restrict__ p)
{
    float4 u = *reinterpret_cast<const float4*>(p);
    float4 v = *reinterpret_cast<const float4*>(p + 4);
    bf16x8 r;
    r[0]=(__bf16)u.x; r[1]=(__bf16)u.y; r[2]=(__bf16)u.z; r[3]=(__bf16)u.w;
    r[4]=(__bf16)v.x; r[5]=(__bf16)v.y; r[6]=(__bf16)v.z; r[7]=(__bf16)v.w;
    return r;
}

// ---------------- main: screen + rescue ------------------------------------
// Block = 256 threads (4 waves), each wave 16 tokens; block = 64 tokens x
// 1 group. Grid = 256 tiles * 8 groups = 2048 blocks (8/CU, 32 waves/CU).
__global__ __launch_bounds__(256, 8) void vq_mfma_kernel(
    const float*  __restrict__ x,
    const float*  __restrict__ cb,
    const __bf16* __restrict__ wb,
    const float*  __restrict__ wcn,
    float* __restrict__ out)
{
    __shared__ __bf16 bbufA[STG_ELEM];   // 8 KB
    __shared__ __bf16 bbufB[STG_ELEM];   // 8 KB
    __shared__ float  cn64[NCODE];       // 4 KB

    const int tid  = threadIdx.x;
    const int lane = tid & 63;
    const int wv   = tid >> 6;
    const int g    = blockIdx.x & 7;
    const int tile = blockIdx.x >> 3;

    const __bf16* wbg = wb + (size_t)g * (NCODE * DG);
    const int sbase = tid * 16;          // 16 elems (32 B) per thread

    bf16x8 r0, r1;                       // in-flight stage registers

#define LOADSTG(st) do {                                                  \
    const __bf16* sp_ = wbg + (size_t)(st) * STG_ELEM + sbase;            \
    r0 = *reinterpret_cast<const bf16x8*>(sp_);                           \
    r1 = *reinterpret_cast<const bf16x8*>(sp_ + 8);                       \
} while (0)

#define WRITESTG(bufp) do {                                               \
    __bf16* dp_ = (bufp) + sbase;                                         \
    *reinterpret_cast<bf16x8*>(dp_)     = r0;                             \
    *reinterpret_cast<bf16x8*>(dp_ + 8) = r1;                             \
} while (0)

#define COMPUTESTG(bufp, st) do {                                         \
    _Pragma("unroll 2")                                                   \
    for (int ctl_ = 0; ctl_ < 4; ++ctl_) {                                \
        bf16x8 b0_ = *reinterpret_cast<const bf16x8*>((bufp) + ctl_ * 1024 + lane * 8);        \
        bf16x8 b1_ = *reinterpret_cast<const bf16x8*>((bufp) + ctl_ * 1024 + 512 + lane * 8);  \
        const int code_ = (st) * 64 + ctl_ * 16 + row;                    \
        const float cnv_ = cn64[code_];                                   \
        const f32x4 ci_ = {cnv_, cnv_, cnv_, cnv_};                       \
        f32x4 z_ = __builtin_amdgcn_mfma_f32_16x16x32_bf16(aA, b0_, ci_, 0, 0, 0); \
        f32x4 d_ = __builtin_amdgcn_mfma_f32_16x16x32_bf16(aB, b1_, z_, 0, 0, 0);  \
        asm("" : "+v"(d_));                                               \
        _Pragma("unroll")                                                 \
        for (int r_ = 0; r_ < 4; ++r_) {                                  \
            unsigned key_ = (__float_as_uint(d_[r_]) & 0xFFFFFC00u) | (unsigned)code_; \
            top2_(best[r_], sec[r_], key_);                               \
        }                                                                 \
    }                                                                     \
} while (0)

    // ---- prologue: stage 0 -> regs; cn64; A-fragments; write stage 0 ----
    LOADSTG(0);

    {   // cn+64 (screen bias; rescue uses true wcn)
        float4 v = reinterpret_cast<const float4*>(wcn + g * NCODE)[tid];
        v.x += 64.0f; v.y += 64.0f; v.z += 64.0f; v.w += 64.0f;
        reinterpret_cast<float4*>(cn64)[tid] = v;
    }

    const int row  = lane & 15;
    const int q    = lane >> 4;
    const int k0   = q * 8;
    const int tok0 = tile * 64 + wv * 16;

    bf16x8 aA, aB;
    {
        const float* xr = x + (size_t)(tok0 + row) * DMODEL + g * DG;
        aA = cvt8(xr + k0);
        aB = cvt8(xr + 32 + k0);
        asm("" : "+v"(aA));
        asm("" : "+v"(aB));
    }

    unsigned best[4], sec[4];
    #pragma unroll
    for (int r = 0; r < 4; ++r) { best[r] = 0xFFFFFFFFu; sec[r] = 0xFFFFFFFFu; }

    WRITESTG(bbufA);     // vmcnt wait lands here; ds_write stage 0
    __syncthreads();     // bufA + cn64 visible to all waves

    // ---- 16 stages, double-buffered, one barrier per stage ----
    for (int stp = 0; stp < 8; ++stp) {
        const int stE = stp * 2, stO = stp * 2 + 1;

        LOADSTG(stO);                 // in flight under even compute
        COMPUTESTG(bbufA, stE);
        WRITESTG(bbufB);              // prev bufB readers done (last barrier)
        __syncthreads();              // bufB ready

        if (stp < 7) {
            LOADSTG(stE + 2);         // in flight under odd compute
            COMPUTESTG(bbufB, stO);
            WRITESTG(bbufA);          // prev bufA readers done (last barrier)
            __syncthreads();          // bufA ready
        } else {
            COMPUTESTG(bbufB, stO);   // final stage: no prefetch
        }
    }

    // min-reduce packed keys across each 16-lane col group (q-group)
    unsigned mk[4];
    #pragma unroll
    for (int r = 0; r < 4; ++r) mk[r] = best[r];
    #pragma unroll
    for (int mask = 1; mask < 16; mask <<= 1) {
        #pragma unroll
        for (int r = 0; r < 4; ++r) {
            unsigned o = (unsigned)__shfl_xor((int)mk[r], mask, 64);
            mk[r] = umin_(mk[r], o);
        }
    }

    const float* cbg  = cb  + (size_t)g * NCODE * DG;
    const float* wcng = wcn + (size_t)g * NCODE;

    #pragma unroll
    for (int r = 0; r < 4; ++r) {
        const unsigned m_ = mk[r];
        int sel = (int)(m_ & 0x3FFu);
        const float thr = __uint_as_float(m_ & 0xFFFFFC00u) + EPS;
        const float bd  = __uint_as_float(best[r] & 0xFFFFFC00u);
        const float sdd = __uint_as_float(sec[r]  & 0xFFFFFC00u);
        const bool oth = (bd <= thr && best[r] != m_) || (sdd <= thr);
        const unsigned long long bal = __ballot(oth);
        if (((bal >> (q * 16)) & 0xFFFFULL) != 0ULL) {
            // exact fp32 rescue among tracked candidates
            const int token = tok0 + q * 4 + r;
            const float* xr = x + (size_t)token * DMODEL + g * DG;
            const float xn = dotc(xr, xr);
            float ed = 1e30f; int ei = 0x7FFFFFFF;
            if (bd <= thr) {
                const int cc = (int)(best[r] & 0x3FFu);
                float dd = (xn + wcng[cc]) - 2.0f * dotc(xr, cbg + (size_t)cc * DG);
                if (dd < ed || (dd == ed && cc < ei)) { ed = dd; ei = cc; }
            }
            if (sdd <= thr) {
                const int cc = (int)(sec[r] & 0x3FFu);
                float dd = (xn + wcng[cc]) - 2.0f * dotc(xr, cbg + (size_t)cc * DG);
                if (dd < ed || (dd == ed && cc < ei)) { ed = dd; ei = cc; }
            }
            #pragma unroll
            for (int mask = 1; mask < 16; mask <<= 1) {
                float pd = __shfl_xor(ed, mask, 64);
                int   pi = __shfl_xor(ei, mask, 64);
                if (pd < ed || (pd == ed && pi < ei)) { ed = pd; ei = pi; }
            }
            sel = ei;
        }
        // write the selected code row (16 lanes x float4 = 64 floats)
        const int token = tok0 + q * 4 + r;
        const float4 src = reinterpret_cast<const float4*>(cbg + (size_t)sel * DG)[row];
        reinterpret_cast<float4*>(out + (size_t)token * DMODEL + g * DG)[row] = src;
    }
#undef LOADSTG
#undef WRITESTG
#undef COMPUTESTG
}

// ---------------- fp32 fallback (ws too small) -----------------------------
__global__ __launch_bounds__(512, 4) void vq_fp32_kernel(
    const float* __restrict__ x,
    const float* __restrict__ cb,
    float* __restrict__ out)
{
    __shared__ float cnl[NGRP][NCODE];
    const int tid  = threadIdx.x;
    const int lane = tid & 63;
    const int wave = tid >> 6;
    const int g    = __builtin_amdgcn_readfirstlane(wave);
    const int token = blockIdx.x * 64 + lane;
    const float* __restrict__ cbg = cb + (size_t)g * NCODE * DG;

    for (int kk = lane; kk < NCODE; kk += 64) {
        const float4* c4 = reinterpret_cast<const float4*>(cbg + kk * DG);
        float s = 0.0f;
        #pragma unroll
        for (int j = 0; j < 16; ++j) {
            float4 v = c4[j];
            s = fmaf(v.x, v.x, s); s = fmaf(v.y, v.y, s);
            s = fmaf(v.z, v.z, s); s = fmaf(v.w, v.w, s);
        }
        cnl[g][kk] = s;
    }
    __syncthreads();

    const float* xr = x + (size_t)token * DMODEL + g * DG;
    float xn = dotc(xr, xr);
    float bestv = 3.4e38f; int bidx = 0;
    for (int k = 0; k < NCODE; ++k) {
        float dist = (xn + cnl[g][k]) - 2.0f * dotc(xr, cbg + (size_t)k * DG);
        if (dist < bestv) { bestv = dist; bidx = k; }
    }
    const float4* q4 = reinterpret_cast<const float4*>(cbg + (size_t)bidx * DG);
    float4* o4 = reinterpret_cast<float4*>(out + (size_t)token * DMODEL + g * DG);
    #pragma unroll
    for (int j = 0; j < 16; ++j) o4[j] = q4[j];
}

extern "C" void kernel_launch(void* const* d_in, const int* in_sizes, int n_in,
                              void* d_out, int out_size, void* d_ws, size_t ws_size,
                              hipStream_t stream) {
    const float* x  = (const float*)d_in[0];
    const float* cb = (const float*)d_in[1];
    float* out = (float*)d_out;

    const size_t wb_bytes = (size_t)NGRP * NCODE * DG * sizeof(__bf16); // 1 MB
    const size_t cn_bytes = (size_t)NGRP * NCODE * sizeof(float);       // 32 KB
    if (ws_size < wb_bytes + cn_bytes) {
        vq_fp32_kernel<<<256, 512, 0, stream>>>(x, cb, out);
        return;
    }
    __bf16* wb  = (__bf16*)d_ws;
    float*  wcn = (float*)((char*)d_ws + wb_bytes);

    prep_frags<<<256, 256, 0, stream>>>(cb, wb);
    prep_cnorm<<<32, 256, 0, stream>>>(cb, wcn);
    vq_mfma_kernel<<<2048, 256, 0, stream>>>(x, cb, wb, wcn, out);
}

// Round 18
// 63.172 us; speedup vs baseline: 1.1788x; 1.1262x over previous
//
#include <hip/hip_runtime.h>

// Grouped VQ: bf16-MFMA screen + exact-fp32 rescue, v18.
// = v12 (63us, proven) + TWO safe VALU cuts; select reverted to v12's
// proven med3 top-2 (v17's pair-wise form was wrong in its degenerate
// k0==k1 use: med3(b,k,k)=k loses the old best when k<b).
// (1) xn precomputed per token into LDS at prologue.
// (2) dotc4 (4-way ILP) for rescue candidate dots (refcheck'd in v14).
// Numerics class unchanged: d = cn64[code] + <x,-2c>_bf16 (C-folded MFMA),
// 22-bit key | 10-bit code, EPS=0.10, exact-fp32 rescue, lowest-index ties.

#define NTOK   16384
#define DMODEL 512
#define NGRP   8
#define DG     64
#define NCODE  1024
#define EPS    0.10f

#define STG_ELEM 8192        // 8 ct-tiles * 1024 bf16 = 16 KB

typedef __attribute__((ext_vector_type(8))) __bf16 bf16x8;
typedef __attribute__((ext_vector_type(4))) float  f32x4;

__device__ __forceinline__ unsigned umin_(unsigned a, unsigned b){ return a<b?a:b; }

// exact running top-2 (PROVEN v11/v12): best' = min(bo,k),
// sec' = median{bo, sec, k}  (bo = old best; bo <= sec invariant).
__device__ __forceinline__ void top2_(unsigned& best, unsigned& sec, unsigned key)
{
    unsigned bo = best;
    best = umin_(bo, key);
    unsigned ns;
    asm("v_med3_u32 %0, %1, %2, %3" : "=v"(ns) : "v"(bo), "v"(sec), "v"(key));
    sec = ns;
}

// ---------------- prep: pack codebook into B-fragment layout (bf16) --------
// Stores -2*c. ws_b element index = (((g*64 + ct)*2 + s)*64 + lane)*8 + j
//   holds -2*cb[g][ct*16 + (lane&15)][s*32 + (lane>>4)*8 + j] as bf16.
__global__ __launch_bounds__(256) void prep_frags(
    const float* __restrict__ cb, __bf16* __restrict__ wb)
{
    int tid  = blockIdx.x * 256 + threadIdx.x;      // 0..65535
    int lane = tid & 63;
    int s    = (tid >> 6) & 1;
    int ct   = (tid >> 7) & 63;
    int g    = tid >> 13;
    int code = ct * 16 + (lane & 15);
    int k0   = s * 32 + (lane >> 4) * 8;
    const float* src = cb + ((size_t)g * NCODE + code) * DG + k0;
    bf16x8 v;
    #pragma unroll
    for (int j = 0; j < 8; ++j) v[j] = (__bf16)(-2.0f * src[j]);
    *reinterpret_cast<bf16x8*>(wb + (size_t)tid * 8) = v;
}

__global__ __launch_bounds__(256) void prep_cnorm(
    const float* __restrict__ cb, float* __restrict__ wcn)
{
    int i = blockIdx.x * 256 + threadIdx.x;         // 0..8191 (g*1024+code)
    const float4* c4 = reinterpret_cast<const float4*>(cb + (size_t)i * DG);
    float s = 0.0f;
    #pragma unroll
    for (int j = 0; j < 16; ++j) {
        float4 v = c4[j];
        s = fmaf(v.x, v.x, s); s = fmaf(v.y, v.y, s);
        s = fmaf(v.z, v.z, s); s = fmaf(v.w, v.w, s);
    }
    wcn[i] = s;
}

// sequential-order fp32 dot (reference-faithful; prologue xn).
__device__ __forceinline__ float dotc(const float* __restrict__ a,
                                      const float* __restrict__ b)
{
    const float4* a4 = reinterpret_cast<const float4*>(a);
    const float4* b4 = reinterpret_cast<const float4*>(b);
    float s = 0.0f;
    #pragma unroll 4
    for (int j = 0; j < 16; ++j) {
        float4 u = a4[j], v = b4[j];
        s = fmaf(u.x, v.x, s); s = fmaf(u.y, v.y, s);
        s = fmaf(u.z, v.z, s); s = fmaf(u.w, v.w, s);
    }
    return s;
}

// 4-way-split fp32 dot (serial depth 16); rescue candidate dots.
__device__ __forceinline__ float dotc4(const float* __restrict__ a,
                                       const float* __restrict__ b)
{
    const float4* a4 = reinterpret_cast<const float4*>(a);
    const float4* b4 = reinterpret_cast<const float4*>(b);
    float s0 = 0.0f, s1 = 0.0f, s2 = 0.0f, s3 = 0.0f;
    #pragma unroll
    for (int j = 0; j < 16; ++j) {
        float4 u = a4[j], v = b4[j];
        s0 = fmaf(u.x, v.x, s0); s1 = fmaf(u.y, v.y, s1);
        s2 = fmaf(u.z, v.z, s2); s3 = fmaf(u.w, v.w, s3);
    }
    return (s0 + s1) + (s2 + s3);
}

__device__ __forceinline__ bf16x8 cvt8(const float* __restrict__ p)
{
    float4 u = *reinterpret_cast<const float4*>(p);
    float4 v = *reinterpret_cast<const float4*>(p + 4);
    bf16x8 r;
    r[0]=(__bf16)u.x; r[1]=(__bf16)u.y; r[2]=(__bf16)u.z; r[3]=(__bf16)u.w;
    r[4]=(__bf16)v.x; r[5]=(__bf16)v.y; r[6]=(__bf16)v.z; r[7]=(__bf16)v.w;
    return r;
}

// ---------------- main: screen + rescue ------------------------------------
// Block = 256 threads (4 waves), each wave 32 tokens; block = 128 tokens x
// 1 group. Grid = 128 tiles * 8 groups = 1024 blocks.
__global__ __launch_bounds__(256, 4) void vq_mfma_kernel(
    const float*  __restrict__ x,
    const float*  __restrict__ cb,
    const __bf16* __restrict__ wb,
    const float*  __restrict__ wcn,
    float* __restrict__ out)
{
    __shared__ __bf16 bbufA[STG_ELEM];   // 16 KB
    __shared__ __bf16 bbufB[STG_ELEM];   // 16 KB
    __shared__ float  cn64[NCODE];       //  4 KB
    __shared__ float  xnl[128];          // 0.5 KB: per-token x_norm

    const int tid  = threadIdx.x;
    const int lane = tid & 63;
    const int wv   = tid >> 6;
    const int g    = blockIdx.x & 7;
    const int tile = blockIdx.x >> 3;

    const __bf16* wbg = wb + (size_t)g * (NCODE * DG);
    const int sbase = wv * 2048 + lane * 8;   // element offset within a stage

    bf16x8 r0, r1, r2, r3;   // in-flight stage registers

#define LOADSTG(st) do {                                                  \
    const __bf16* sp_ = wbg + (size_t)(st) * STG_ELEM + sbase;            \
    r0 = *reinterpret_cast<const bf16x8*>(sp_);                           \
    r1 = *reinterpret_cast<const bf16x8*>(sp_ + 512);                     \
    r2 = *reinterpret_cast<const bf16x8*>(sp_ + 1024);                    \
    r3 = *reinterpret_cast<const bf16x8*>(sp_ + 1536);                    \
} while (0)

#define WRITESTG(bufp) do {                                               \
    __bf16* dp_ = (bufp) + sbase;                                         \
    *reinterpret_cast<bf16x8*>(dp_)        = r0;                          \
    *reinterpret_cast<bf16x8*>(dp_ + 512)  = r1;                          \
    *reinterpret_cast<bf16x8*>(dp_ + 1024) = r2;                          \
    *reinterpret_cast<bf16x8*>(dp_ + 1536) = r3;                          \
} while (0)

#define COMPUTESTG(bufp, st) do {                                         \
    _Pragma("unroll 2")                                                   \
    for (int ctl_ = 0; ctl_ < 8; ++ctl_) {                                \
        bf16x8 b0_ = *reinterpret_cast<const bf16x8*>((bufp) + ctl_ * 1024 + lane * 8);        \
        bf16x8 b1_ = *reinterpret_cast<const bf16x8*>((bufp) + ctl_ * 1024 + 512 + lane * 8);  \
        const int code_ = (st) * 128 + ctl_ * 16 + row;                   \
        const float cnv_ = cn64[code_];                                   \
        const f32x4 ci_ = {cnv_, cnv_, cnv_, cnv_};                       \
        _Pragma("unroll")                                                 \
        for (int s_ = 0; s_ < 2; ++s_) {                                  \
            f32x4 z_ = __builtin_amdgcn_mfma_f32_16x16x32_bf16(aA[s_], b0_, ci_, 0, 0, 0); \
            f32x4 d_ = __builtin_amdgcn_mfma_f32_16x16x32_bf16(aB[s_], b1_, z_, 0, 0, 0);  \
            asm("" : "+v"(d_));                                           \
            _Pragma("unroll")                                             \
            for (int r_ = 0; r_ < 4; ++r_) {                              \
                unsigned key_ = (__float_as_uint(d_[r_]) & 0xFFFFFC00u) | (unsigned)code_; \
                top2_(best[s_][r_], sec[s_][r_], key_);                   \
            }                                                             \
        }                                                                 \
    }                                                                     \
} while (0)

    // ---- prologue: stage 0 -> regs; cn64; xn; A-fragments; write stage 0 ----
    LOADSTG(0);

    {   // cn+64 (screen bias; rescue uses true wcn)
        float4 v = reinterpret_cast<const float4*>(wcn + g * NCODE)[tid];
        v.x += 64.0f; v.y += 64.0f; v.z += 64.0f; v.w += 64.0f;
        reinterpret_cast<float4*>(cn64)[tid] = v;
    }

    const int row  = lane & 15;
    const int q    = lane >> 4;
    const int k0   = q * 8;
    const int tok0 = tile * 128 + wv * 32;
    const int btok0 = tile * 128;

    // per-token x_norm into LDS (threads 0..127; reference order)
    if (tid < 128) {
        const float* xr = x + (size_t)(btok0 + tid) * DMODEL + g * DG;
        xnl[tid] = dotc(xr, xr);
    }

    bf16x8 aA[2], aB[2];
    #pragma unroll
    for (int s = 0; s < 2; ++s) {
        const float* xr = x + (size_t)(tok0 + s * 16 + row) * DMODEL + g * DG;
        aA[s] = cvt8(xr + k0);
        aB[s] = cvt8(xr + 32 + k0);
        asm("" : "+v"(aA[s]));
        asm("" : "+v"(aB[s]));
    }

    unsigned best[2][4], sec[2][4];
    #pragma unroll
    for (int s = 0; s < 2; ++s)
        #pragma unroll
        for (int r = 0; r < 4; ++r) { best[s][r] = 0xFFFFFFFFu; sec[s][r] = 0xFFFFFFFFu; }

    WRITESTG(bbufA);     // vmcnt wait lands here; ds_write stage 0
    __syncthreads();     // bufA + cn64 + xnl visible to all waves

    // ---- 8 stages, double-buffered, one barrier per stage ----
    for (int stp = 0; stp < 4; ++stp) {
        const int stE = stp * 2, stO = stp * 2 + 1;

        LOADSTG(stO);                 // in flight under even compute
        COMPUTESTG(bbufA, stE);
        WRITESTG(bbufB);              // prev bufB readers done (last barrier)
        __syncthreads();              // bufB ready

        if (stp < 3) {
            LOADSTG(stE + 2);         // in flight under odd compute
            COMPUTESTG(bbufB, stO);
            WRITESTG(bbufA);          // prev bufA readers done (last barrier)
            __syncthreads();          // bufA ready
        } else {
            COMPUTESTG(bbufB, stO);   // final stage: no prefetch
        }
    }

    // min-reduce packed keys across each 16-lane col group (q-group)
    unsigned mk[2][4];
    #pragma unroll
    for (int s = 0; s < 2; ++s)
        #pragma unroll
        for (int r = 0; r < 4; ++r) mk[s][r] = best[s][r];
    #pragma unroll
    for (int mask = 1; mask < 16; mask <<= 1) {
        #pragma unroll
        for (int s = 0; s < 2; ++s)
            #pragma unroll
            for (int r = 0; r < 4; ++r) {
                unsigned o = (unsigned)__shfl_xor((int)mk[s][r], mask, 64);
                mk[s][r] = umin_(mk[s][r], o);
            }
    }

    const float* cbg  = cb  + (size_t)g * NCODE * DG;
    const float* wcng = wcn + (size_t)g * NCODE;

    #pragma unroll
    for (int s = 0; s < 2; ++s) {
        #pragma unroll
        for (int r = 0; r < 4; ++r) {
            const unsigned m_ = mk[s][r];
            int sel = (int)(m_ & 0x3FFu);
            const float thr = __uint_as_float(m_ & 0xFFFFFC00u) + EPS;
            const float bd  = __uint_as_float(best[s][r] & 0xFFFFFC00u);
            const float sdd = __uint_as_float(sec[s][r]  & 0xFFFFFC00u);
            const bool oth = (bd <= thr && best[s][r] != m_) || (sdd <= thr);
            const unsigned long long bal = __ballot(oth);
            if (((bal >> (q * 16)) & 0xFFFFULL) != 0ULL) {
                // exact fp32 rescue among tracked candidates (xn from LDS)
                const int token = tok0 + s * 16 + q * 4 + r;
                const float* xr = x + (size_t)token * DMODEL + g * DG;
                const float xn = xnl[token - btok0];
                float ed = 1e30f; int ei = 0x7FFFFFFF;
                if (bd <= thr) {
                    const int cc = (int)(best[s][r] & 0x3FFu);
                    float dd = (xn + wcng[cc]) - 2.0f * dotc4(xr, cbg + (size_t)cc * DG);
                    if (dd < ed || (dd == ed && cc < ei)) { ed = dd; ei = cc; }
                }
                if (sdd <= thr) {
                    const int cc = (int)(sec[s][r] & 0x3FFu);
                    float dd = (xn + wcng[cc]) - 2.0f * dotc4(xr, cbg + (size_t)cc * DG);
                    if (dd < ed || (dd == ed && cc < ei)) { ed = dd; ei = cc; }
                }
                #pragma unroll
                for (int mask = 1; mask < 16; mask <<= 1) {
                    float pd = __shfl_xor(ed, mask, 64);
                    int   pi = __shfl_xor(ei, mask, 64);
                    if (pd < ed || (pd == ed && pi < ei)) { ed = pd; ei = pi; }
                }
                sel = ei;
            }
            // write the selected code row (16 lanes x float4 = 64 floats)
            const int token = tok0 + s * 16 + q * 4 + r;
            const float4 src = reinterpret_cast<const float4*>(cbg + (size_t)sel * DG)[row];
            reinterpret_cast<float4*>(out + (size_t)token * DMODEL + g * DG)[row] = src;
        }
    }
#undef LOADSTG
#undef WRITESTG
#undef COMPUTESTG
}

// ---------------- fp32 fallback (ws too small) -----------------------------
__global__ __launch_bounds__(512, 4) void vq_fp32_kernel(
    const float* __restrict__ x,
    const float* __restrict__ cb,
    float* __restrict__ out)
{
    __shared__ float cnl[NGRP][NCODE];
    const int tid  = threadIdx.x;
    const int lane = tid & 63;
    const int wave = tid >> 6;
    const int g    = __builtin_amdgcn_readfirstlane(wave);
    const int token = blockIdx.x * 64 + lane;
    const float* __restrict__ cbg = cb + (size_t)g * NCODE * DG;

    for (int kk = lane; kk < NCODE; kk += 64) {
        const float4* c4 = reinterpret_cast<const float4*>(cbg + kk * DG);
        float s = 0.0f;
        #pragma unroll
        for (int j = 0; j < 16; ++j) {
            float4 v = c4[j];
            s = fmaf(v.x, v.x, s); s = fmaf(v.y, v.y, s);
            s = fmaf(v.z, v.z, s); s = fmaf(v.w, v.w, s);
        }
        cnl[g][kk] = s;
    }
    __syncthreads();

    const float* xr = x + (size_t)token * DMODEL + g * DG;
    float xn = dotc(xr, xr);
    float bestv = 3.4e38f; int bidx = 0;
    for (int k = 0; k < NCODE; ++k) {
        float dist = (xn + cnl[g][k]) - 2.0f * dotc(xr, cbg + (size_t)k * DG);
        if (dist < bestv) { bestv = dist; bidx = k; }
    }
    const float4* q4 = reinterpret_cast<const float4*>(cbg + (size_t)bidx * DG);
    float4* o4 = reinterpret_cast<float4*>(out + (size_t)token * DMODEL + g * DG);
    #pragma unroll
    for (int j = 0; j < 16; ++j) o4[j] = q4[j];
}

extern "C" void kernel_launch(void* const* d_in, const int* in_sizes, int n_in,
                              void* d_out, int out_size, void* d_ws, size_t ws_size,
                              hipStream_t stream) {
    const float* x  = (const float*)d_in[0];
    const float* cb = (const float*)d_in[1];
    float* out = (float*)d_out;

    const size_t wb_bytes = (size_t)NGRP * NCODE * DG * sizeof(__bf16); // 1 MB
    const size_t cn_bytes = (size_t)NGRP * NCODE * sizeof(float);       // 32 KB
    if (ws_size < wb_bytes + cn_bytes) {
        vq_fp32_kernel<<<256, 512, 0, stream>>>(x, cb, out);
        return;
    }
    __bf16* wb  = (__bf16*)d_ws;
    float*  wcn = (float*)((char*)d_ws + wb_bytes);

    prep_frags<<<256, 256, 0, stream>>>(cb, wb);
    prep_cnorm<<<32, 256, 0, stream>>>(cb, wcn);
    vq_mfma_kernel<<<1024, 256, 0, stream>>>(x, cb, wb, wcn, out);
}